// Round 22
// baseline (803.383 us; speedup 1.0000x reference)
//
#include <hip/hip_runtime.h>
#include <hip/hip_bf16.h>

typedef __hip_bfloat16 bf16;
typedef __attribute__((ext_vector_type(8))) __bf16 bf16x8;
typedef __attribute__((ext_vector_type(4))) float f32x4;

#define NB 32
#define NQ 300
#define NK 2048
#define NH 8

#define MFMA(a, b, c) __builtin_amdgcn_mfma_f32_16x16x32_bf16(a, b, c, 0, 0, 0)

__device__ __forceinline__ bf16x8 cvt8(float4 a, float4 b) {
    bf16x8 r;
    r[0] = (__bf16)a.x; r[1] = (__bf16)a.y; r[2] = (__bf16)a.z; r[3] = (__bf16)a.w;
    r[4] = (__bf16)b.x; r[5] = (__bf16)b.y; r[6] = (__bf16)b.z; r[7] = (__bf16)b.w;
    return r;
}
__device__ __forceinline__ bf16x8 loadA_f32(const float* p) {
    return cvt8(*(const float4*)p, *(const float4*)(p + 4));
}
__device__ __forceinline__ unsigned pkbf(float a, float b) {
    union { __bf16 h; unsigned short u; } ua, ub;
    ua.h = (__bf16)a; ub.h = (__bf16)b;
    return (unsigned)ua.u | ((unsigned)ub.u << 16);
}

// ---------------------------------------------------------------------------
// wprep: 7 weight matrices [256][256] fp32 -> bf16. order: qc qp kc kp v qs o
// ---------------------------------------------------------------------------
__global__ __launch_bounds__(256) void wprep_kernel(
    const float* __restrict__ w0, const float* __restrict__ w1,
    const float* __restrict__ w2, const float* __restrict__ w3,
    const float* __restrict__ w4, const float* __restrict__ w5,
    const float* __restrict__ w6, bf16* __restrict__ wbf)
{
    const float* Ws[7] = {w0, w1, w2, w3, w4, w5, w6};
    size_t e = ((size_t)blockIdx.x * 256 + threadIdx.x) * 8;
    const float* src = Ws[e >> 16] + (e & 65535);
    bf16x8 v = loadA_f32(src);
    *(bf16x8*)(wbf + e) = v;
}

// ---------------------------------------------------------------------------
// qproj (merged): q_full[..+d]    = 0.125*(hidden@qc^T+qc_b + qpos@qp^T+qp_b)
//                 q_full[..+32+d] = 0.125*(sine@qs^T+qs_b)
// ---------------------------------------------------------------------------
__global__ __launch_bounds__(128) void qproj_kernel(
    const float* __restrict__ XH, const float* __restrict__ XP,
    const float* __restrict__ XS,
    const bf16* __restrict__ WC, const bf16* __restrict__ WP,
    const bf16* __restrict__ WS,
    const float* __restrict__ bc, const float* __restrict__ bp,
    const float* __restrict__ bs, bf16* __restrict__ q_full)
{
    const int t = threadIdx.x, w = t >> 6, l = t & 63, g = l >> 4, c16 = l & 15;
    const int rbase = blockIdx.x * 32 + w * 16;
    const int row = rbase + c16;

    bf16x8 ah[8], ap[8], as_[8];
    #pragma unroll
    for (int ks = 0; ks < 8; ++ks) {
        ah[ks]  = loadA_f32(XH + (size_t)row * 256 + ks * 32 + g * 8);
        ap[ks]  = loadA_f32(XP + (size_t)row * 256 + ks * 32 + g * 8);
        as_[ks] = loadA_f32(XS + (size_t)row * 256 + ks * 32 + g * 8);
    }
    for (int nt = 0; nt < 16; ++nt) {
        const int n = nt * 16 + c16;
        f32x4 accc = {0.f, 0.f, 0.f, 0.f}, accs = {0.f, 0.f, 0.f, 0.f};
        #pragma unroll
        for (int ks = 0; ks < 8; ++ks) {
            bf16x8 bwc = *(const bf16x8*)(WC + (size_t)n * 256 + ks * 32 + g * 8);
            bf16x8 bwp = *(const bf16x8*)(WP + (size_t)n * 256 + ks * 32 + g * 8);
            bf16x8 bws = *(const bf16x8*)(WS + (size_t)n * 256 + ks * 32 + g * 8);
            accc = MFMA(ah[ks], bwc, accc);
            accc = MFMA(ap[ks], bwp, accc);
            accs = MFMA(as_[ks], bws, accs);
        }
        const float bic = bc[n] + bp[n], bis = bs[n];
        const int h = n >> 5, d = n & 31;
        #pragma unroll
        for (int i = 0; i < 4; ++i) {
            const int r = rbase + 4 * g + i;
            const int b_ = (int)(((unsigned)r * 55925u) >> 24);   // r/300
            const int q = r - b_ * 300;
            const size_t base = (((size_t)b_ * 8 + h) * NQ + q) * 64;
            q_full[base + d]      = __float2bfloat16((accc[i] + bic) * 0.125f);
            q_full[base + 32 + d] = __float2bfloat16((accs[i] + bis) * 0.125f);
        }
    }
}

// ---------------------------------------------------------------------------
// kvproj v4 (INSTRUMENTED x5 rep): X1/X2 staged as bf16 in padded LDS
// ([2][64][264], 16B pad => <=2-way bank conflicts). A-frags become
// ds_read_b128; VGPR drops ~200 -> ~80 so 2 blocks/CU x 4 waves = 4/SIMD
// (occupancy theory). Math + v3 epilogue identical. Rep is idempotent.
// Per-rep cost = (total - 304) / 5.
// ---------------------------------------------------------------------------
__global__ __launch_bounds__(256) void kvproj_kernel(
    const float* __restrict__ X1, const float* __restrict__ X2,
    const bf16* __restrict__ W1, const bf16* __restrict__ W2,
    const bf16* __restrict__ WV,
    const float* __restrict__ b1, const float* __restrict__ b2,
    const float* __restrict__ bvb,
    bf16* __restrict__ k_full, bf16* __restrict__ v_t)
{
    __shared__ __align__(16) bf16 xs[2][64][264];   // 67.6 KB

    const int t = threadIdx.x, w = t >> 6, l = t & 63, g = l >> 4, c16 = l & 15;
    const int wm = w >> 1, wn = w & 1;
    const int r0 = blockIdx.x * 64;

#define LDA(INP, mt, ks) \
    (*(const bf16x8*)&xs[INP][wm * 32 + (mt) * 16 + c16][(ks) * 32 + g * 8])

    #pragma unroll 1
    for (int rep = 0; rep < 5; ++rep) {
        // ---- stage X1, X2 -> LDS (bf16) ----
        for (int i = t; i < 2048; i += 256) {
            const int row = i >> 5, cc = i & 31;
            bf16x8 v1 = loadA_f32(X1 + (size_t)(r0 + row) * 256 + cc * 8);
            bf16x8 v2 = loadA_f32(X2 + (size_t)(r0 + row) * 256 + cc * 8);
            *(bf16x8*)&xs[0][row][cc * 8] = v1;
            *(bf16x8*)&xs[1][row][cc * 8] = v2;
        }
        __syncthreads();

        #pragma unroll 1
        for (int nt = 0; nt < 8; ++nt) {
            const int n  = wn * 128 + nt * 16 + c16;    // v-orientation
            const int n0 = wn * 128 + nt * 16 + 4 * g;  // k^T-orientation
            f32x4 tc0 = {0.f,0.f,0.f,0.f}, tc1 = {0.f,0.f,0.f,0.f};
            f32x4 tp0 = {0.f,0.f,0.f,0.f}, tp1 = {0.f,0.f,0.f,0.f};
            f32x4 av0 = {0.f,0.f,0.f,0.f}, av1 = {0.f,0.f,0.f,0.f};
            #pragma unroll
            for (int ks = 0; ks < 8; ++ks) {
                bf16x8 bw1 = *(const bf16x8*)(W1 + (size_t)n * 256 + ks * 32 + g * 8);
                bf16x8 bw2 = *(const bf16x8*)(W2 + (size_t)n * 256 + ks * 32 + g * 8);
                bf16x8 bwv = *(const bf16x8*)(WV + (size_t)n * 256 + ks * 32 + g * 8);
                bf16x8 a10 = LDA(0, 0, ks), a11 = LDA(0, 1, ks);
                bf16x8 a20 = LDA(1, 0, ks), a21 = LDA(1, 1, ks);
                tc0 = MFMA(bw1, a10, tc0);   // transposed: A=W, B=X
                tp0 = MFMA(bw2, a20, tp0);
                av0 = MFMA(a10, bwv, av0);   // original: A=X, B=W
                tc1 = MFMA(bw1, a11, tc1);
                tp1 = MFMA(bw2, a21, tp1);
                av1 = MFMA(a11, bwv, av1);
            }
            const f32x4 bc4 = *(const f32x4*)(b1 + n0);
            const f32x4 bp4 = *(const f32x4*)(b2 + n0);
            const float bvn = bvb[n];
            const int h0 = n0 >> 5, d0 = n0 & 31;
            const int hv = n >> 5,  dv = n & 31;
            #pragma unroll
            for (int mt = 0; mt < 2; ++mt) {
                f32x4 tc = mt ? tc1 : tc0;
                f32x4 tp = mt ? tp1 : tp0;
                const int kq = r0 + wm * 32 + mt * 16 + c16;
                const int bk = kq >> 11, kkq = kq & 2047;
                const size_t kb = ((size_t)(bk * 8 + h0) * NK + kkq) * 64;
                const float y0 = tp[0] + bp4[0], y1 = tp[1] + bp4[1];
                const float y2 = tp[2] + bp4[2], y3 = tp[3] + bp4[3];
                uint2 kc2 = { pkbf(tc[0] + bc4[0] + y0, tc[1] + bc4[1] + y1),
                              pkbf(tc[2] + bc4[2] + y2, tc[3] + bc4[3] + y3) };
                uint2 kp2 = { pkbf(y0, y1), pkbf(y2, y3) };
                *(uint2*)&k_full[kb + d0]      = kc2;
                *(uint2*)&k_full[kb + 32 + d0] = kp2;
                f32x4 av = mt ? av1 : av0;
                const int rr = r0 + wm * 32 + mt * 16 + 4 * g;
                const int bv = rr >> 11, kkv = rr & 2047;
                uint2 vpk = { pkbf(av[0] + bvn, av[1] + bvn),
                              pkbf(av[2] + bvn, av[3] + bvn) };
                *(uint2*)&v_t[((size_t)(bv * 8 + hv) * 32 + dv) * NK + kkv] = vpk;
            }
        }
        __syncthreads();   // protect LDS before next rep's staging
    }
#undef LDA
}

// ---------------------------------------------------------------------------
// attn (MERGED attn1+attn2): block = (bh, 64 q); wave w owns k quarter
// [512w, 512w+512) for ALL 4 q-tiles. Phase A: partial denominators ->
// psum -> barrier -> invt. Phase B: probs (nt stores) + PV; cross-wave
// O reduce via 32 KB smem.
// ---------------------------------------------------------------------------
__global__ __launch_bounds__(256) void attn_kernel(
    const bf16* __restrict__ q_full, const bf16* __restrict__ k_full,
    const bf16* __restrict__ v_t, float* __restrict__ w_out,
    float* __restrict__ attn_tmp)
{
    __shared__ float psum[4][64];
    __shared__ __align__(16) unsigned smem[8192];   // 32 KB: paw now, red later

    const int t = threadIdx.x, w = t >> 6, l = t & 63;
    const int g = l >> 4, c16 = l & 15;
    const int s4 = (c16 & 3) << 2;

    const int p = blockIdx.x;
    const int lid = (p & 7) * 160 + (p >> 3);
    const int bh = (int)(((unsigned)lid * 6554u) >> 15);   // lid/5 (lid<1280)
    const int blk = lid - bh * 5;
    const int q0b = blk * 64;

    const size_t qbase = (size_t)bh * NQ * 64;
    const size_t kbase = (size_t)bh * NK * 64;
    const size_t vbase = (size_t)bh * 32 * NK;

    bf16x8 qf0[4], qf1[4];
    float* wrow[4];
    bool qok[4];
    #pragma unroll
    for (int qt = 0; qt < 4; ++qt) {
        const int qq = q0b + qt * 16 + c16;
        const int qr = min(qq, NQ - 1);
        qf0[qt] = *(const bf16x8*)(q_full + qbase + (size_t)qr * 64 + g * 8);
        qf1[qt] = *(const bf16x8*)(q_full + qbase + (size_t)qr * 64 + 32 + g * 8);
        wrow[qt] = w_out + ((size_t)bh * NQ + qr) * NK;
        qok[qt] = qq < NQ;
    }

    const int kw0 = w * 512;
    const bf16* kbp = k_full + kbase;
    const bf16* vbp = v_t + vbase;
    unsigned* pawW = smem + w * 2048;   // wave-private: [parity][tile][256]

#define LDK(c, K00, K01, K10, K11) do { \
    const bf16* _kap = kbp + (size_t)(kw0 + (c) * 32 + c16) * 64 + g * 8; \
    K00 = *(const bf16x8*)(_kap); \
    K01 = *(const bf16x8*)(_kap + 32); \
    K10 = *(const bf16x8*)(_kap + 16 * 64); \
    K11 = *(const bf16x8*)(_kap + 16 * 64 + 32); \
} while (0)
#define LDV(c, V0, V1) do { \
    const bf16* _vp = vbp + (size_t)c16 * NK + kw0 + (c) * 32 + g * 8; \
    V0 = *(const bf16x8*)(_vp); \
    V1 = *(const bf16x8*)(_vp + 16 * NK); \
} while (0)

    // ---- phase A: partial denominators over this wave's k quarter ----
    float sums[4] = {0.f, 0.f, 0.f, 0.f};

#define SBODY(c, K00, K01, K10, K11) do { \
    const int _cn = ((c) + 2 < 16) ? (c) + 2 : (c); \
    _Pragma("unroll") \
    for (int _qt = 0; _qt < 4; ++_qt) { \
        f32x4 _slo = {0.f,0.f,0.f,0.f}, _shi = {0.f,0.f,0.f,0.f}; \
        _slo = MFMA(K00, qf0[_qt], _slo); _slo = MFMA(K01, qf1[_qt], _slo); \
        _shi = MFMA(K10, qf0[_qt], _shi); _shi = MFMA(K11, qf1[_qt], _shi); \
        if (_qt == 3) LDK(_cn, K00, K01, K10, K11); \
        sums[_qt] += __expf(_slo[0]) + __expf(_slo[1]) \
                   + __expf(_slo[2]) + __expf(_slo[3]) \
                   + __expf(_shi[0]) + __expf(_shi[1]) \
                   + __expf(_shi[2]) + __expf(_shi[3]); \
    } \
} while (0)

    {
        bf16x8 Ak00, Ak01, Ak10, Ak11;
        bf16x8 Bk00, Bk01, Bk10, Bk11;
        LDK(0, Ak00, Ak01, Ak10, Ak11);
        LDK(1, Bk00, Bk01, Bk10, Bk11);
        for (int c = 0; c < 16; c += 2) {
            SBODY(c,     Ak00, Ak01, Ak10, Ak11);
            SBODY(c + 1, Bk00, Bk01, Bk10, Bk11);
        }
    }
#undef SBODY

    #pragma unroll
    for (int qt = 0; qt < 4; ++qt) {
        sums[qt] += __shfl_xor(sums[qt], 16);
        sums[qt] += __shfl_xor(sums[qt], 32);
    }
    if (l < 16) {
        #pragma unroll
        for (int qt = 0; qt < 4; ++qt) psum[w][qt * 16 + l] = sums[qt];
    }
    __syncthreads();

    float invt[4];
    #pragma unroll
    for (int qt = 0; qt < 4; ++qt) {
        const int qi = qt * 16 + c16;
        invt[qt] = 1.f / (psum[0][qi] + psum[1][qi] + psum[2][qi] + psum[3][qi]);
    }

    // ---- phase B: probs + PV over the same k quarter (K now L1/L2-warm) ----
    f32x4 oa0[4], oa1[4];
    #pragma unroll
    for (int qt = 0; qt < 4; ++qt) {
        oa0[qt] = (f32x4){0.f, 0.f, 0.f, 0.f};
        oa1[qt] = (f32x4){0.f, 0.f, 0.f, 0.f};
    }

#define BODY(c, PAR, K00, K01, K10, K11, V0, V1) do { \
    const int _k0 = kw0 + (c) * 32; \
    const int _cn = ((c) + 2 < 16) ? (c) + 2 : (c); \
    unsigned* _paw = pawW + (PAR) * 1024; \
    _Pragma("unroll") \
    for (int _qt = 0; _qt < 4; ++_qt) { \
        f32x4 _slo = {0.f,0.f,0.f,0.f}, _shi = {0.f,0.f,0.f,0.f}; \
        _slo = MFMA(K00, qf0[_qt], _slo); _slo = MFMA(K01, qf1[_qt], _slo); \
        _shi = MFMA(K10, qf0[_qt], _shi); _shi = MFMA(K11, qf1[_qt], _shi); \
        if (_qt == 3) LDK(_cn, K00, K01, K10, K11); \
        float _plo[4], _phi[4]; \
        _Pragma("unroll") \
        for (int _i = 0; _i < 4; ++_i) { \
            _plo[_i] = __expf(_slo[_i]) * invt[_qt]; \
            _phi[_i] = __expf(_shi[_i]) * invt[_qt]; \
        } \
        if (qok[_qt]) { \
            f32x4 _vlo = {_plo[0], _plo[1], _plo[2], _plo[3]}; \
            f32x4 _vhi = {_phi[0], _phi[1], _phi[2], _phi[3]}; \
            __builtin_nontemporal_store(_vlo, (f32x4*)(wrow[_qt] + _k0 + 4 * g)); \
            __builtin_nontemporal_store(_vhi, (f32x4*)(wrow[_qt] + _k0 + 16 + 4 * g)); \
        } \
        unsigned* _pq = _paw + _qt * 256; \
        uint2 _lo2 = { pkbf(_plo[0], _plo[1]), pkbf(_plo[2], _plo[3]) }; \
        uint2 _hi2 = { pkbf(_phi[0], _phi[1]), pkbf(_phi[2], _phi[3]) }; \
        *(uint2*)&_pq[c16 * 16 + ((2 * g) ^ s4)]     = _lo2; \
        *(uint2*)&_pq[c16 * 16 + ((8 + 2 * g) ^ s4)] = _hi2; \
        union { uint4 q; bf16x8 v; } _A; \
        _A.q = *(uint4*)&_pq[c16 * 16 + ((4 * g) ^ s4)]; \
        oa0[_qt] = MFMA(_A.v, V0, oa0[_qt]); \
        oa1[_qt] = MFMA(_A.v, V1, oa1[_qt]); \
        if (_qt == 3) LDV(_cn, V0, V1); \
    } \
} while (0)

    {
        bf16x8 Ak00, Ak01, Ak10, Ak11, Av0, Av1;
        bf16x8 Bk00, Bk01, Bk10, Bk11, Bv0, Bv1;
        LDK(0, Ak00, Ak01, Ak10, Ak11);  LDV(0, Av0, Av1);
        LDK(1, Bk00, Bk01, Bk10, Bk11);  LDV(1, Bv0, Bv1);

        for (int c = 0; c < 16; c += 2) {
            BODY(c,     0, Ak00, Ak01, Ak10, Ak11, Av0, Av1);
            BODY(c + 1, 1, Bk00, Bk01, Bk10, Bk11, Bv0, Bv1);
        }
    }
#undef BODY
#undef LDV
#undef LDK

    // partial O -> own smem region (overlaps own paw area; wave-private)
    float* redw = (float*)smem + w * 2048;   // [64 q][32 d]
    #pragma unroll
    for (int qt = 0; qt < 4; ++qt) {
        #pragma unroll
        for (int i = 0; i < 4; ++i) {
            const int q = qt * 16 + 4 * g + i;
            redw[q * 32 + c16]      = oa0[qt][i];
            redw[q * 32 + 16 + c16] = oa1[qt][i];
        }
    }
    __syncthreads();

    // cross-wave O reduce: 2048 elements / 256 threads
    const float* redf = (const float*)smem;
    const int b_ = bh >> 3, h = bh & 7;
    #pragma unroll
    for (int i = 0; i < 8; ++i) {
        const int idx = t + 256 * i;
        const int q = idx >> 5, d = idx & 31;
        if (q0b + q < NQ)
            attn_tmp[((size_t)b_ * NQ + q0b + q) * 256 + h * 32 + d] =
                redf[0 * 2048 + q * 32 + d] + redf[1 * 2048 + q * 32 + d] +
                redf[2 * 2048 + q * 32 + d] + redf[3 * 2048 + q * 32 + d];
    }
}

// ---------------------------------------------------------------------------
// oproj: out = attn_tmp @ o^T + o_b (fp32 out). 150 blocks.
// ---------------------------------------------------------------------------
__global__ __launch_bounds__(256) void oproj_kernel(
    const float* __restrict__ X1, const bf16* __restrict__ W1,
    const float* __restrict__ b1, float* __restrict__ out)
{
    const int t = threadIdx.x, w = t >> 6, l = t & 63, g = l >> 4, c16 = l & 15;
    const int wm = w >> 1, wn = w & 1;
    const int r0 = blockIdx.x * 64 + wm * 32;

    bf16x8 a1[2][8];
    #pragma unroll
    for (int mt = 0; mt < 2; ++mt) {
        const int row = r0 + mt * 16 + c16;
        #pragma unroll
        for (int ks = 0; ks < 8; ++ks)
            a1[mt][ks] = loadA_f32(X1 + (size_t)row * 256 + ks * 32 + g * 8);
    }
    #pragma unroll
    for (int nt = 0; nt < 8; ++nt) {
        const int n = wn * 128 + nt * 16 + c16;
        f32x4 acc0 = {0.f,0.f,0.f,0.f}, acc1 = {0.f,0.f,0.f,0.f};
        #pragma unroll
        for (int ks = 0; ks < 8; ++ks) {
            bf16x8 bw1 = *(const bf16x8*)(W1 + (size_t)n * 256 + ks * 32 + g * 8);
            acc0 = MFMA(a1[0][ks], bw1, acc0);
            acc1 = MFMA(a1[1][ks], bw1, acc1);
        }
        const float bias = b1[n];
        #pragma unroll
        for (int mt = 0; mt < 2; ++mt) {
            f32x4 acc = mt ? acc1 : acc0;
            #pragma unroll
            for (int i = 0; i < 4; ++i) {
                const int r = r0 + mt * 16 + 4 * g + i;
                out[(size_t)r * 256 + n] = acc[i] + bias;
            }
        }
    }
}

// ---------------------------------------------------------------------------
extern "C" void kernel_launch(void* const* d_in, const int* in_sizes, int n_in,
                              void* d_out, int out_size, void* d_ws, size_t ws_size,
                              hipStream_t stream) {
    const float* hidden = (const float*)d_in[0];
    const float* enc    = (const float*)d_in[1];
    const float* sine   = (const float*)d_in[2];
    const float* encpos = (const float*)d_in[3];
    const float* qpos   = (const float*)d_in[4];
    const float* qc_w = (const float*)d_in[5];  const float* qc_b = (const float*)d_in[6];
    const float* qp_w = (const float*)d_in[7];  const float* qp_b = (const float*)d_in[8];
    const float* kc_w = (const float*)d_in[9];  const float* kc_b = (const float*)d_in[10];
    const float* kp_w = (const float*)d_in[11]; const float* kp_b = (const float*)d_in[12];
    const float* v_w  = (const float*)d_in[13]; const float* v_b  = (const float*)d_in[14];
    const float* qs_w = (const float*)d_in[15]; const float* qs_b = (const float*)d_in[16];
    const float* o_w  = (const float*)d_in[17]; const float* o_b  = (const float*)d_in[18];

    float* out = (float*)d_out;
    float* attn_out = out;                          // [B][Q][256]
    float* w_out    = out + (size_t)NB * NQ * 256;  // [B][NH][Q][K]

    char* ws = (char*)d_ws;
    bf16* q_full    = (bf16*)ws;                        //  9,830,400
    bf16* k_full    = (bf16*)(ws + 9830400);            // 67,108,864
    bf16* v_t       = (bf16*)(ws + 76939264);           // 33,554,432
    float* attn_tmp = (float*)(ws + 110493696);         //  9,830,400
    bf16* wbf       = (bf16*)(ws + 120324096);          //    917,504

    wprep_kernel<<<224, 256, 0, stream>>>(qc_w, qp_w, kc_w, kp_w, v_w, qs_w, o_w, wbf);

    qproj_kernel<<<300, 128, 0, stream>>>(hidden, qpos, sine,
        wbf + 0 * 65536, wbf + 1 * 65536, wbf + 5 * 65536,
        qc_b, qp_b, qs_b, q_full);
    kvproj_kernel<<<1024, 256, 0, stream>>>(enc, encpos,
        wbf + 2 * 65536, wbf + 3 * 65536, wbf + 4 * 65536,
        kc_b, kp_b, v_b, k_full, v_t);

    attn_kernel<<<1280, 256, 0, stream>>>(q_full, k_full, v_t, w_out, attn_tmp);

    oproj_kernel<<<150, 256, 0, stream>>>(attn_tmp, wbf + 6 * 65536, o_b, attn_out);
}

// Round 23
// 391.102 us; speedup vs baseline: 2.0542x; 2.0542x over previous
//
#include <hip/hip_runtime.h>
#include <hip/hip_bf16.h>

typedef __hip_bfloat16 bf16;
typedef __attribute__((ext_vector_type(8))) __bf16 bf16x8;
typedef __attribute__((ext_vector_type(4))) float f32x4;

#define NB 32
#define NQ 300
#define NK 2048
#define NH 8

#define MFMA(a, b, c) __builtin_amdgcn_mfma_f32_16x16x32_bf16(a, b, c, 0, 0, 0)

__device__ __forceinline__ bf16x8 cvt8(float4 a, float4 b) {
    bf16x8 r;
    r[0] = (__bf16)a.x; r[1] = (__bf16)a.y; r[2] = (__bf16)a.z; r[3] = (__bf16)a.w;
    r[4] = (__bf16)b.x; r[5] = (__bf16)b.y; r[6] = (__bf16)b.z; r[7] = (__bf16)b.w;
    return r;
}
__device__ __forceinline__ bf16x8 loadA_f32(const float* p) {
    return cvt8(*(const float4*)p, *(const float4*)(p + 4));
}
__device__ __forceinline__ unsigned pkbf(float a, float b) {
    union { __bf16 h; unsigned short u; } ua, ub;
    ua.h = (__bf16)a; ub.h = (__bf16)b;
    return (unsigned)ua.u | ((unsigned)ub.u << 16);
}

// ---------------------------------------------------------------------------
// wprep: 7 weight matrices [256][256] fp32 -> bf16. order: qc qp kc kp v qs o
// ---------------------------------------------------------------------------
__global__ __launch_bounds__(256) void wprep_kernel(
    const float* __restrict__ w0, const float* __restrict__ w1,
    const float* __restrict__ w2, const float* __restrict__ w3,
    const float* __restrict__ w4, const float* __restrict__ w5,
    const float* __restrict__ w6, bf16* __restrict__ wbf)
{
    const float* Ws[7] = {w0, w1, w2, w3, w4, w5, w6};
    size_t e = ((size_t)blockIdx.x * 256 + threadIdx.x) * 8;
    const float* src = Ws[e >> 16] + (e & 65535);
    bf16x8 v = loadA_f32(src);
    *(bf16x8*)(wbf + e) = v;
}

// ---------------------------------------------------------------------------
// qproj v2 (2x parallelism: 600 blocks x 128 thr; block = 16 rows; wave w
// owns nt range [8w, 8w+8) -> n in [128w, 128w+128). Same math per (row,n).
// q_full[..+d] = 0.125*(hidden@qc^T+qc_b + qpos@qp^T+qp_b)
// q_full[..+32+d] = 0.125*(sine@qs^T+qs_b)
// ---------------------------------------------------------------------------
__global__ __launch_bounds__(128) void qproj_kernel(
    const float* __restrict__ XH, const float* __restrict__ XP,
    const float* __restrict__ XS,
    const bf16* __restrict__ WC, const bf16* __restrict__ WP,
    const bf16* __restrict__ WS,
    const float* __restrict__ bc, const float* __restrict__ bp,
    const float* __restrict__ bs, bf16* __restrict__ q_full)
{
    const int t = threadIdx.x, w = t >> 6, l = t & 63, g = l >> 4, c16 = l & 15;
    const int rbase = blockIdx.x * 16;
    const int row = rbase + c16;

    bf16x8 ah[8], ap[8], as_[8];
    #pragma unroll
    for (int ks = 0; ks < 8; ++ks) {
        ah[ks]  = loadA_f32(XH + (size_t)row * 256 + ks * 32 + g * 8);
        ap[ks]  = loadA_f32(XP + (size_t)row * 256 + ks * 32 + g * 8);
        as_[ks] = loadA_f32(XS + (size_t)row * 256 + ks * 32 + g * 8);
    }
    for (int nt = 0; nt < 8; ++nt) {
        const int n = w * 128 + nt * 16 + c16;
        f32x4 accc = {0.f, 0.f, 0.f, 0.f}, accs = {0.f, 0.f, 0.f, 0.f};
        #pragma unroll
        for (int ks = 0; ks < 8; ++ks) {
            bf16x8 bwc = *(const bf16x8*)(WC + (size_t)n * 256 + ks * 32 + g * 8);
            bf16x8 bwp = *(const bf16x8*)(WP + (size_t)n * 256 + ks * 32 + g * 8);
            bf16x8 bws = *(const bf16x8*)(WS + (size_t)n * 256 + ks * 32 + g * 8);
            accc = MFMA(ah[ks], bwc, accc);
            accc = MFMA(ap[ks], bwp, accc);
            accs = MFMA(as_[ks], bws, accs);
        }
        const float bic = bc[n] + bp[n], bis = bs[n];
        const int h = n >> 5, d = n & 31;
        #pragma unroll
        for (int i = 0; i < 4; ++i) {
            const int r = rbase + 4 * g + i;
            const int b_ = (int)(((unsigned)r * 55925u) >> 24);   // r/300
            const int q = r - b_ * 300;
            const size_t base = (((size_t)b_ * 8 + h) * NQ + q) * 64;
            q_full[base + d]      = __float2bfloat16((accc[i] + bic) * 0.125f);
            q_full[base + 32 + d] = __float2bfloat16((accs[i] + bis) * 0.125f);
        }
    }
}

// ---------------------------------------------------------------------------
// kvproj v3 (REVERTED from v4: LDS staging gave 114 vs 120 us — null, and
// 67.6KB LDS capped occupancy at 23%): 2x2 waves; k_c/k_p transposed
// (uint2 stores), v original orientation.
// ---------------------------------------------------------------------------
__global__ __launch_bounds__(256) void kvproj_kernel(
    const float* __restrict__ X1, const float* __restrict__ X2,
    const bf16* __restrict__ W1, const bf16* __restrict__ W2,
    const bf16* __restrict__ WV,
    const float* __restrict__ b1, const float* __restrict__ b2,
    const float* __restrict__ bvb,
    bf16* __restrict__ k_full, bf16* __restrict__ v_t)
{
    const int t = threadIdx.x, w = t >> 6, l = t & 63, g = l >> 4, c16 = l & 15;
    const int wm = w >> 1, wn = w & 1;
    const int r0 = blockIdx.x * 64 + wm * 32;

    bf16x8 a1[2][8], a2[2][8];
    #pragma unroll
    for (int mt = 0; mt < 2; ++mt) {
        const int row = r0 + mt * 16 + c16;
        #pragma unroll
        for (int ks = 0; ks < 8; ++ks) {
            a1[mt][ks] = loadA_f32(X1 + (size_t)row * 256 + ks * 32 + g * 8);
            a2[mt][ks] = loadA_f32(X2 + (size_t)row * 256 + ks * 32 + g * 8);
        }
    }
    #pragma unroll
    for (int nt = 0; nt < 8; ++nt) {
        const int n  = wn * 128 + nt * 16 + c16;    // v-orientation (col=c16)
        const int n0 = wn * 128 + nt * 16 + 4 * g;  // k^T-orientation row base
        f32x4 tc0 = {0.f,0.f,0.f,0.f}, tc1 = {0.f,0.f,0.f,0.f};
        f32x4 tp0 = {0.f,0.f,0.f,0.f}, tp1 = {0.f,0.f,0.f,0.f};
        f32x4 av0 = {0.f,0.f,0.f,0.f}, av1 = {0.f,0.f,0.f,0.f};
        #pragma unroll
        for (int ks = 0; ks < 8; ++ks) {
            bf16x8 bw1 = *(const bf16x8*)(W1 + (size_t)n * 256 + ks * 32 + g * 8);
            bf16x8 bw2 = *(const bf16x8*)(W2 + (size_t)n * 256 + ks * 32 + g * 8);
            bf16x8 bwv = *(const bf16x8*)(WV + (size_t)n * 256 + ks * 32 + g * 8);
            tc0 = MFMA(bw1, a1[0][ks], tc0);   // transposed: A=W, B=X
            tp0 = MFMA(bw2, a2[0][ks], tp0);
            av0 = MFMA(a1[0][ks], bwv, av0);   // original: A=X, B=W
            tc1 = MFMA(bw1, a1[1][ks], tc1);
            tp1 = MFMA(bw2, a2[1][ks], tp1);
            av1 = MFMA(a1[1][ks], bwv, av1);
        }
        const f32x4 bc4 = *(const f32x4*)(b1 + n0);
        const f32x4 bp4 = *(const f32x4*)(b2 + n0);
        const float bvn = bvb[n];
        const int h0 = n0 >> 5, d0 = n0 & 31;
        const int hv = n >> 5,  dv = n & 31;
        #pragma unroll
        for (int mt = 0; mt < 2; ++mt) {
            f32x4 tc = mt ? tc1 : tc0;
            f32x4 tp = mt ? tp1 : tp0;
            const int kq = r0 + mt * 16 + c16;
            const int bk = kq >> 11, kkq = kq & 2047;
            const size_t kb = ((size_t)(bk * 8 + h0) * NK + kkq) * 64;
            const float y0 = tp[0] + bp4[0], y1 = tp[1] + bp4[1];
            const float y2 = tp[2] + bp4[2], y3 = tp[3] + bp4[3];
            uint2 kc2 = { pkbf(tc[0] + bc4[0] + y0, tc[1] + bc4[1] + y1),
                          pkbf(tc[2] + bc4[2] + y2, tc[3] + bc4[3] + y3) };
            uint2 kp2 = { pkbf(y0, y1), pkbf(y2, y3) };
            *(uint2*)&k_full[kb + d0]      = kc2;
            *(uint2*)&k_full[kb + 32 + d0] = kp2;
            f32x4 av = mt ? av1 : av0;
            const int rr = r0 + mt * 16 + 4 * g;
            const int bv = rr >> 11, kkv = rr & 2047;
            uint2 vpk = { pkbf(av[0] + bvn, av[1] + bvn),
                          pkbf(av[2] + bvn, av[3] + bvn) };
            *(uint2*)&v_t[((size_t)(bv * 8 + hv) * 32 + dv) * NK + kkv] = vpk;
        }
    }
}

// ---------------------------------------------------------------------------
// attn (MERGED, R21-proven): block = (bh, 64 q); wave w owns k quarter
// [512w, 512w+512) for ALL 4 q-tiles. Phase A: partial denominators ->
// psum -> barrier -> invt. Phase B: probs (nt stores) + PV; cross-wave
// O reduce via 32 KB smem.
// ---------------------------------------------------------------------------
__global__ __launch_bounds__(256) void attn_kernel(
    const bf16* __restrict__ q_full, const bf16* __restrict__ k_full,
    const bf16* __restrict__ v_t, float* __restrict__ w_out,
    float* __restrict__ attn_tmp)
{
    __shared__ float psum[4][64];
    __shared__ __align__(16) unsigned smem[8192];   // 32 KB: paw now, red later

    const int t = threadIdx.x, w = t >> 6, l = t & 63;
    const int g = l >> 4, c16 = l & 15;
    const int s4 = (c16 & 3) << 2;

    const int p = blockIdx.x;
    const int lid = (p & 7) * 160 + (p >> 3);
    const int bh = (int)(((unsigned)lid * 6554u) >> 15);   // lid/5 (lid<1280)
    const int blk = lid - bh * 5;
    const int q0b = blk * 64;

    const size_t qbase = (size_t)bh * NQ * 64;
    const size_t kbase = (size_t)bh * NK * 64;
    const size_t vbase = (size_t)bh * 32 * NK;

    bf16x8 qf0[4], qf1[4];
    float* wrow[4];
    bool qok[4];
    #pragma unroll
    for (int qt = 0; qt < 4; ++qt) {
        const int qq = q0b + qt * 16 + c16;
        const int qr = min(qq, NQ - 1);
        qf0[qt] = *(const bf16x8*)(q_full + qbase + (size_t)qr * 64 + g * 8);
        qf1[qt] = *(const bf16x8*)(q_full + qbase + (size_t)qr * 64 + 32 + g * 8);
        wrow[qt] = w_out + ((size_t)bh * NQ + qr) * NK;
        qok[qt] = qq < NQ;
    }

    const int kw0 = w * 512;
    const bf16* kbp = k_full + kbase;
    const bf16* vbp = v_t + vbase;
    unsigned* pawW = smem + w * 2048;   // wave-private: [parity][tile][256]

#define LDK(c, K00, K01, K10, K11) do { \
    const bf16* _kap = kbp + (size_t)(kw0 + (c) * 32 + c16) * 64 + g * 8; \
    K00 = *(const bf16x8*)(_kap); \
    K01 = *(const bf16x8*)(_kap + 32); \
    K10 = *(const bf16x8*)(_kap + 16 * 64); \
    K11 = *(const bf16x8*)(_kap + 16 * 64 + 32); \
} while (0)
#define LDV(c, V0, V1) do { \
    const bf16* _vp = vbp + (size_t)c16 * NK + kw0 + (c) * 32 + g * 8; \
    V0 = *(const bf16x8*)(_vp); \
    V1 = *(const bf16x8*)(_vp + 16 * NK); \
} while (0)

    // ---- phase A: partial denominators over this wave's k quarter ----
    float sums[4] = {0.f, 0.f, 0.f, 0.f};

#define SBODY(c, K00, K01, K10, K11) do { \
    const int _cn = ((c) + 2 < 16) ? (c) + 2 : (c); \
    _Pragma("unroll") \
    for (int _qt = 0; _qt < 4; ++_qt) { \
        f32x4 _slo = {0.f,0.f,0.f,0.f}, _shi = {0.f,0.f,0.f,0.f}; \
        _slo = MFMA(K00, qf0[_qt], _slo); _slo = MFMA(K01, qf1[_qt], _slo); \
        _shi = MFMA(K10, qf0[_qt], _shi); _shi = MFMA(K11, qf1[_qt], _shi); \
        if (_qt == 3) LDK(_cn, K00, K01, K10, K11); \
        sums[_qt] += __expf(_slo[0]) + __expf(_slo[1]) \
                   + __expf(_slo[2]) + __expf(_slo[3]) \
                   + __expf(_shi[0]) + __expf(_shi[1]) \
                   + __expf(_shi[2]) + __expf(_shi[3]); \
    } \
} while (0)

    {
        bf16x8 Ak00, Ak01, Ak10, Ak11;
        bf16x8 Bk00, Bk01, Bk10, Bk11;
        LDK(0, Ak00, Ak01, Ak10, Ak11);
        LDK(1, Bk00, Bk01, Bk10, Bk11);
        for (int c = 0; c < 16; c += 2) {
            SBODY(c,     Ak00, Ak01, Ak10, Ak11);
            SBODY(c + 1, Bk00, Bk01, Bk10, Bk11);
        }
    }
#undef SBODY

    #pragma unroll
    for (int qt = 0; qt < 4; ++qt) {
        sums[qt] += __shfl_xor(sums[qt], 16);
        sums[qt] += __shfl_xor(sums[qt], 32);
    }
    if (l < 16) {
        #pragma unroll
        for (int qt = 0; qt < 4; ++qt) psum[w][qt * 16 + l] = sums[qt];
    }
    __syncthreads();

    float invt[4];
    #pragma unroll
    for (int qt = 0; qt < 4; ++qt) {
        const int qi = qt * 16 + c16;
        invt[qt] = 1.f / (psum[0][qi] + psum[1][qi] + psum[2][qi] + psum[3][qi]);
    }

    // ---- phase B: probs + PV over the same k quarter (K now L1/L2-warm) ----
    f32x4 oa0[4], oa1[4];
    #pragma unroll
    for (int qt = 0; qt < 4; ++qt) {
        oa0[qt] = (f32x4){0.f, 0.f, 0.f, 0.f};
        oa1[qt] = (f32x4){0.f, 0.f, 0.f, 0.f};
    }

#define BODY(c, PAR, K00, K01, K10, K11, V0, V1) do { \
    const int _k0 = kw0 + (c) * 32; \
    const int _cn = ((c) + 2 < 16) ? (c) + 2 : (c); \
    unsigned* _paw = pawW + (PAR) * 1024; \
    _Pragma("unroll") \
    for (int _qt = 0; _qt < 4; ++_qt) { \
        f32x4 _slo = {0.f,0.f,0.f,0.f}, _shi = {0.f,0.f,0.f,0.f}; \
        _slo = MFMA(K00, qf0[_qt], _slo); _slo = MFMA(K01, qf1[_qt], _slo); \
        _shi = MFMA(K10, qf0[_qt], _shi); _shi = MFMA(K11, qf1[_qt], _shi); \
        if (_qt == 3) LDK(_cn, K00, K01, K10, K11); \
        float _plo[4], _phi[4]; \
        _Pragma("unroll") \
        for (int _i = 0; _i < 4; ++_i) { \
            _plo[_i] = __expf(_slo[_i]) * invt[_qt]; \
            _phi[_i] = __expf(_shi[_i]) * invt[_qt]; \
        } \
        if (qok[_qt]) { \
            f32x4 _vlo = {_plo[0], _plo[1], _plo[2], _plo[3]}; \
            f32x4 _vhi = {_phi[0], _phi[1], _phi[2], _phi[3]}; \
            __builtin_nontemporal_store(_vlo, (f32x4*)(wrow[_qt] + _k0 + 4 * g)); \
            __builtin_nontemporal_store(_vhi, (f32x4*)(wrow[_qt] + _k0 + 16 + 4 * g)); \
        } \
        unsigned* _pq = _paw + _qt * 256; \
        uint2 _lo2 = { pkbf(_plo[0], _plo[1]), pkbf(_plo[2], _plo[3]) }; \
        uint2 _hi2 = { pkbf(_phi[0], _phi[1]), pkbf(_phi[2], _phi[3]) }; \
        *(uint2*)&_pq[c16 * 16 + ((2 * g) ^ s4)]     = _lo2; \
        *(uint2*)&_pq[c16 * 16 + ((8 + 2 * g) ^ s4)] = _hi2; \
        union { uint4 q; bf16x8 v; } _A; \
        _A.q = *(uint4*)&_pq[c16 * 16 + ((4 * g) ^ s4)]; \
        oa0[_qt] = MFMA(_A.v, V0, oa0[_qt]); \
        oa1[_qt] = MFMA(_A.v, V1, oa1[_qt]); \
        if (_qt == 3) LDV(_cn, V0, V1); \
    } \
} while (0)

    {
        bf16x8 Ak00, Ak01, Ak10, Ak11, Av0, Av1;
        bf16x8 Bk00, Bk01, Bk10, Bk11, Bv0, Bv1;
        LDK(0, Ak00, Ak01, Ak10, Ak11);  LDV(0, Av0, Av1);
        LDK(1, Bk00, Bk01, Bk10, Bk11);  LDV(1, Bv0, Bv1);

        for (int c = 0; c < 16; c += 2) {
            BODY(c,     0, Ak00, Ak01, Ak10, Ak11, Av0, Av1);
            BODY(c + 1, 1, Bk00, Bk01, Bk10, Bk11, Bv0, Bv1);
        }
    }
#undef BODY
#undef LDV
#undef LDK

    // partial O -> own smem region (overlaps own paw area; wave-private)
    float* redw = (float*)smem + w * 2048;   // [64 q][32 d]
    #pragma unroll
    for (int qt = 0; qt < 4; ++qt) {
        #pragma unroll
        for (int i = 0; i < 4; ++i) {
            const int q = qt * 16 + 4 * g + i;
            redw[q * 32 + c16]      = oa0[qt][i];
            redw[q * 32 + 16 + c16] = oa1[qt][i];
        }
    }
    __syncthreads();

    // cross-wave O reduce: 2048 elements / 256 threads
    const float* redf = (const float*)smem;
    const int b_ = bh >> 3, h = bh & 7;
    #pragma unroll
    for (int i = 0; i < 8; ++i) {
        const int idx = t + 256 * i;
        const int q = idx >> 5, d = idx & 31;
        if (q0b + q < NQ)
            attn_tmp[((size_t)b_ * NQ + q0b + q) * 256 + h * 32 + d] =
                redf[0 * 2048 + q * 32 + d] + redf[1 * 2048 + q * 32 + d] +
                redf[2 * 2048 + q * 32 + d] + redf[3 * 2048 + q * 32 + d];
    }
}

// ---------------------------------------------------------------------------
// oproj v2 (2x parallelism: 600 blocks x 128 thr; block = 16 rows; wave w
// owns n in [128w, 128w+128)). out = attn_tmp @ o^T + o_b (fp32 out).
// ---------------------------------------------------------------------------
__global__ __launch_bounds__(128) void oproj_kernel(
    const float* __restrict__ X1, const bf16* __restrict__ W1,
    const float* __restrict__ b1, float* __restrict__ out)
{
    const int t = threadIdx.x, w = t >> 6, l = t & 63, g = l >> 4, c16 = l & 15;
    const int rbase = blockIdx.x * 16;
    const int row = rbase + c16;

    bf16x8 a1[8];
    #pragma unroll
    for (int ks = 0; ks < 8; ++ks)
        a1[ks] = loadA_f32(X1 + (size_t)row * 256 + ks * 32 + g * 8);

    for (int nt = 0; nt < 8; ++nt) {
        const int n = w * 128 + nt * 16 + c16;
        f32x4 acc = {0.f, 0.f, 0.f, 0.f};
        #pragma unroll
        for (int ks = 0; ks < 8; ++ks) {
            bf16x8 bw1 = *(const bf16x8*)(W1 + (size_t)n * 256 + ks * 32 + g * 8);
            acc = MFMA(a1[ks], bw1, acc);
        }
        const float bias = b1[n];
        #pragma unroll
        for (int i = 0; i < 4; ++i) {
            const int r = rbase + 4 * g + i;
            out[(size_t)r * 256 + n] = acc[i] + bias;
        }
    }
}

// ---------------------------------------------------------------------------
extern "C" void kernel_launch(void* const* d_in, const int* in_sizes, int n_in,
                              void* d_out, int out_size, void* d_ws, size_t ws_size,
                              hipStream_t stream) {
    const float* hidden = (const float*)d_in[0];
    const float* enc    = (const float*)d_in[1];
    const float* sine   = (const float*)d_in[2];
    const float* encpos = (const float*)d_in[3];
    const float* qpos   = (const float*)d_in[4];
    const float* qc_w = (const float*)d_in[5];  const float* qc_b = (const float*)d_in[6];
    const float* qp_w = (const float*)d_in[7];  const float* qp_b = (const float*)d_in[8];
    const float* kc_w = (const float*)d_in[9];  const float* kc_b = (const float*)d_in[10];
    const float* kp_w = (const float*)d_in[11]; const float* kp_b = (const float*)d_in[12];
    const float* v_w  = (const float*)d_in[13]; const float* v_b  = (const float*)d_in[14];
    const float* qs_w = (const float*)d_in[15]; const float* qs_b = (const float*)d_in[16];
    const float* o_w  = (const float*)d_in[17]; const float* o_b  = (const float*)d_in[18];

    float* out = (float*)d_out;
    float* attn_out = out;                          // [B][Q][256]
    float* w_out    = out + (size_t)NB * NQ * 256;  // [B][NH][Q][K]

    char* ws = (char*)d_ws;
    bf16* q_full    = (bf16*)ws;                        //  9,830,400
    bf16* k_full    = (bf16*)(ws + 9830400);            // 67,108,864
    bf16* v_t       = (bf16*)(ws + 76939264);           // 33,554,432
    float* attn_tmp = (float*)(ws + 110493696);         //  9,830,400
    bf16* wbf       = (bf16*)(ws + 120324096);          //    917,504

    wprep_kernel<<<224, 256, 0, stream>>>(qc_w, qp_w, kc_w, kp_w, v_w, qs_w, o_w, wbf);

    qproj_kernel<<<600, 128, 0, stream>>>(hidden, qpos, sine,
        wbf + 0 * 65536, wbf + 1 * 65536, wbf + 5 * 65536,
        qc_b, qp_b, qs_b, q_full);
    kvproj_kernel<<<1024, 256, 0, stream>>>(enc, encpos,
        wbf + 2 * 65536, wbf + 3 * 65536, wbf + 4 * 65536,
        kc_b, kp_b, v_b, k_full, v_t);

    attn_kernel<<<1280, 256, 0, stream>>>(q_full, k_full, v_t, w_out, attn_tmp);

    oproj_kernel<<<600, 128, 0, stream>>>(attn_tmp, wbf + 6 * 65536, o_b, attn_out);
}